// Round 3
// baseline (3681.934 us; speedup 1.0000x reference)
//
#include <hip/hip_runtime.h>
#include <cstdint>
#include <cstddef>

#define CH    1024
#define LAT   128
#define NBLK  256   // one block per CU; block owns 4 hidden dims (16 gate rows)

// ---------------- ws layout (bytes) ----------------
// [0, 16 KiB)    : hbuf64[2][1024] tagged h broadcast (u64: tag<<32 | bits)
// [+16 KiB]      : hfin64[1024]    tagged final h (tag==1)
// [+24 KiB]      : cfin64[1024]    tagged final c (tag==1)
// [+32 KiB]      : ctrl[1]         {eos_idx}
#define WS_HBUF  0
#define WS_HFIN  16384
#define WS_CFIN  (16384 + 8192)
#define WS_CTRL  (16384 + 16384)

__device__ __forceinline__ float sigmf(float x) { return 1.0f / (1.0f + expf(-x)); }

// ---------------- kernel A: eos index ----------------
__global__ __launch_bounds__(1024) void setup_k(const int* __restrict__ tok,
                                                int* __restrict__ ctrl) {
  __shared__ int red[1024];
  int tid = threadIdx.x;
  red[tid] = (tok[tid] == 1) ? tid : 0x7fffffff;
  __syncthreads();
  for (int s = 512; s > 0; s >>= 1) {
    if (tid < s) red[tid] = min(red[tid], red[tid + s]);
    __syncthreads();
  }
  if (tid == 0) {
    int e = red[0];
    ctrl[0] = (e == 0x7fffffff) ? 0 : e;
  }
}

// ---------------- kernel B: fused LSTM recurrence + input GEMM + projections ----------------
// 256 blocks x 256 threads (4 waves). Wave w owns hidden dim d = b*4+w.
// Lane l: gate q=l>>4 (i,f,g,o), k-chunk m=l&15 (64 contiguous k).
// W_hh and W_ih row-slices live in registers (64 each). x_t slice prefetched
// into registers one step ahead; its dot is computed after publishing h (in
// the poll-idle window), so the input GEMM is off the critical path.
// Cross-block h exchange: fence-free tagged u64 relaxed agent-scope atomics.
__global__ __launch_bounds__(256, 1) void lstm_k(const int* __restrict__ tok,
                                                 const float* __restrict__ h0,
                                                 const float* __restrict__ c0,
                                                 const float* __restrict__ eps,
                                                 const float* __restrict__ emb,
                                                 const float* __restrict__ Wih,
                                                 const float* __restrict__ Whh,
                                                 const float* __restrict__ bih,
                                                 const float* __restrict__ bhh,
                                                 const float* __restrict__ Wm,
                                                 const float* __restrict__ bm,
                                                 const float* __restrict__ Wl,
                                                 const float* __restrict__ bl,
                                                 unsigned long long* __restrict__ hbuf64,
                                                 unsigned long long* __restrict__ hfin64,
                                                 unsigned long long* __restrict__ cfin64,
                                                 const int* __restrict__ ctrl,
                                                 float* __restrict__ out) {
  __shared__ float hs[2][1088];   // swizzled: hs[slot][m*68 + j] = h[m*64+j]
  __shared__ float hcs[2048];
  __shared__ float rs[8];

  const int tid = threadIdx.x;          // 0..255
  const int b   = blockIdx.x;           // 0..255
  const int w   = tid >> 6;             // wave 0..3
  const int l   = tid & 63;
  const int q   = l >> 4;               // gate: 0=i 1=f 2=g 3=o
  const int m   = l & 15;               // k-chunk
  const int d   = b * 4 + w;            // hidden dim owned by this wave
  const int r   = q * 1024 + d;         // gate row

  // ---- load weight slices into registers ----
  float wh[64], wi[64];
  {
    const float* php = Whh + (size_t)r * CH + m * 64;
    const float* pip = Wih + (size_t)r * CH + m * 64;
#pragma unroll
    for (int i = 0; i < 64; i += 4) {
      float4 a = *(const float4*)(php + i);
      wh[i] = a.x; wh[i + 1] = a.y; wh[i + 2] = a.z; wh[i + 3] = a.w;
    }
#pragma unroll
    for (int i = 0; i < 64; i += 4) {
      float4 a = *(const float4*)(pip + i);
      wi[i] = a.x; wi[i + 1] = a.y; wi[i + 2] = a.z; wi[i + 3] = a.w;
    }
  }
  const float binit = bih[r] + bhh[r];
  const int eos = ctrl[0];

  float creg = c0[d];
  float hreg = h0[d];

  // ---- x pipeline prologue: xacc = dot(wi, x_0); xreg = x_1 slice ----
  float xreg[64];
  float xacc = 0.0f;
  {
    const float* x0 = emb + (size_t)tok[0] * CH + m * 64;
#pragma unroll
    for (int i = 0; i < 64; i += 4) {
      float4 a = *(const float4*)(x0 + i);
      xacc += wi[i] * a.x + wi[i + 1] * a.y + wi[i + 2] * a.z + wi[i + 3] * a.w;
    }
    const float* x1 = emb + (size_t)tok[1] * CH + m * 64;
#pragma unroll
    for (int i = 0; i < 64; i += 4) {
      float4 a = *(const float4*)(x1 + i);
      xreg[i] = a.x; xreg[i + 1] = a.y; xreg[i + 2] = a.z; xreg[i + 3] = a.w;
    }
  }

  for (int t = 0; t < eos; t++) {
    // ---- fill hs[t&1]: thread polls 4 tagged values ----
    float4 hv;
    if (t == 0) {
      hv = *(const float4*)(h0 + tid * 4);
    } else {
      const unsigned want = (unsigned)t;
      const unsigned long long* src = hbuf64 + (size_t)(t & 1) * 1024 + tid * 4;
      unsigned long long v0, v1, v2, v3;
      bool ok;
      do {
        v0 = __hip_atomic_load(src + 0, __ATOMIC_RELAXED, __HIP_MEMORY_SCOPE_AGENT);
        v1 = __hip_atomic_load(src + 1, __ATOMIC_RELAXED, __HIP_MEMORY_SCOPE_AGENT);
        v2 = __hip_atomic_load(src + 2, __ATOMIC_RELAXED, __HIP_MEMORY_SCOPE_AGENT);
        v3 = __hip_atomic_load(src + 3, __ATOMIC_RELAXED, __HIP_MEMORY_SCOPE_AGENT);
        ok = ((unsigned)(v0 >> 32) == want) & ((unsigned)(v1 >> 32) == want) &
             ((unsigned)(v2 >> 32) == want) & ((unsigned)(v3 >> 32) == want);
      } while (!ok);
      hv.x = __uint_as_float((unsigned)v0);
      hv.y = __uint_as_float((unsigned)v1);
      hv.z = __uint_as_float((unsigned)v2);
      hv.w = __uint_as_float((unsigned)v3);
    }
    *(float4*)&hs[t & 1][(tid >> 4) * 68 + (tid & 15) * 4] = hv;
    __syncthreads();

    // ---- matvec: acc = dot(wh, h_slice) + xacc ----
    const float* hp = &hs[t & 1][m * 68];
    float acc = xacc;
#pragma unroll
    for (int i = 0; i < 64; i += 4) {
      float4 h4 = *(const float4*)(hp + i);
      acc += wh[i] * h4.x + wh[i + 1] * h4.y + wh[i + 2] * h4.z + wh[i + 3] * h4.w;
    }
    // reduce within 16-lane gate groups
    acc += __shfl_xor(acc, 1);
    acc += __shfl_xor(acc, 2);
    acc += __shfl_xor(acc, 4);
    acc += __shfl_xor(acc, 8);
    float accb = acc + binit;                 // valid at lanes m==0
    float iv = __shfl(accb, 0);
    float fv = __shfl(accb, 16);
    float gv = __shfl(accb, 32);
    float ov = __shfl(accb, 48);
    float cn = sigmf(fv) * creg + sigmf(iv) * tanhf(gv);
    float hn = sigmf(ov) * tanhf(cn);
    creg = cn;
    hreg = hn;
    if (l == 0) {
      unsigned long long pv = ((unsigned long long)(unsigned)(t + 1) << 32) |
                              (unsigned long long)__float_as_uint(hn);
      __hip_atomic_store(&hbuf64[(size_t)((t + 1) & 1) * 1024 + d], pv,
                         __ATOMIC_RELAXED, __HIP_MEMORY_SCOPE_AGENT);
    }

    // ---- off-critical-path: xacc for t+1, prefetch x_{t+2} ----
    float xa = 0.0f;
#pragma unroll
    for (int i = 0; i < 64; i += 4)
      xa += wi[i] * xreg[i] + wi[i + 1] * xreg[i + 1] +
            wi[i + 2] * xreg[i + 2] + wi[i + 3] * xreg[i + 3];
    xacc = xa;
    const int tn = min(t + 2, 1023);
    const float* xp = emb + (size_t)tok[tn] * CH + m * 64;
#pragma unroll
    for (int i = 0; i < 64; i += 4) {
      float4 a = *(const float4*)(xp + i);
      xreg[i] = a.x; xreg[i + 1] = a.y; xreg[i + 2] = a.z; xreg[i + 3] = a.w;
    }
  }

  // ---- publish final h, c (tag == 1) ----
  if (l == 0) {
    unsigned long long ph = (1ull << 32) | (unsigned long long)__float_as_uint(hreg);
    unsigned long long pc = (1ull << 32) | (unsigned long long)__float_as_uint(creg);
    __hip_atomic_store(&hfin64[d], ph, __ATOMIC_RELAXED, __HIP_MEMORY_SCOPE_AGENT);
    __hip_atomic_store(&cfin64[d], pc, __ATOMIC_RELAXED, __HIP_MEMORY_SCOPE_AGENT);
  }
  if (b >= LAT) return;   // blocks 128..255 done

  // ---- gather hc = concat(h, c) ----
  {
    const unsigned long long* hp = hfin64 + tid * 4;
    const unsigned long long* cp = cfin64 + tid * 4;
    unsigned long long v0, v1, v2, v3;
    bool ok;
    do {
      v0 = __hip_atomic_load(hp + 0, __ATOMIC_RELAXED, __HIP_MEMORY_SCOPE_AGENT);
      v1 = __hip_atomic_load(hp + 1, __ATOMIC_RELAXED, __HIP_MEMORY_SCOPE_AGENT);
      v2 = __hip_atomic_load(hp + 2, __ATOMIC_RELAXED, __HIP_MEMORY_SCOPE_AGENT);
      v3 = __hip_atomic_load(hp + 3, __ATOMIC_RELAXED, __HIP_MEMORY_SCOPE_AGENT);
      ok = ((unsigned)(v0 >> 32) == 1u) & ((unsigned)(v1 >> 32) == 1u) &
           ((unsigned)(v2 >> 32) == 1u) & ((unsigned)(v3 >> 32) == 1u);
    } while (!ok);
    hcs[tid * 4 + 0] = __uint_as_float((unsigned)v0);
    hcs[tid * 4 + 1] = __uint_as_float((unsigned)v1);
    hcs[tid * 4 + 2] = __uint_as_float((unsigned)v2);
    hcs[tid * 4 + 3] = __uint_as_float((unsigned)v3);
    do {
      v0 = __hip_atomic_load(cp + 0, __ATOMIC_RELAXED, __HIP_MEMORY_SCOPE_AGENT);
      v1 = __hip_atomic_load(cp + 1, __ATOMIC_RELAXED, __HIP_MEMORY_SCOPE_AGENT);
      v2 = __hip_atomic_load(cp + 2, __ATOMIC_RELAXED, __HIP_MEMORY_SCOPE_AGENT);
      v3 = __hip_atomic_load(cp + 3, __ATOMIC_RELAXED, __HIP_MEMORY_SCOPE_AGENT);
      ok = ((unsigned)(v0 >> 32) == 1u) & ((unsigned)(v1 >> 32) == 1u) &
           ((unsigned)(v2 >> 32) == 1u) & ((unsigned)(v3 >> 32) == 1u);
    } while (!ok);
    hcs[1024 + tid * 4 + 0] = __uint_as_float((unsigned)v0);
    hcs[1024 + tid * 4 + 1] = __uint_as_float((unsigned)v1);
    hcs[1024 + tid * 4 + 2] = __uint_as_float((unsigned)v2);
    hcs[1024 + tid * 4 + 3] = __uint_as_float((unsigned)v3);
  }
  __syncthreads();

  // ---- projections: mean[b], logv[b] (2048-dot each over 256 threads) ----
  float pm = 0.0f, pl = 0.0f;
  {
    const float* wmp = Wm + (size_t)b * 2048 + tid * 8;
    const float* wlp = Wl + (size_t)b * 2048 + tid * 8;
    const float* hcp = &hcs[tid * 8];
#pragma unroll
    for (int j = 0; j < 8; j += 4) {
      float4 wm4 = *(const float4*)(wmp + j);
      float4 wl4 = *(const float4*)(wlp + j);
      float4 hc4 = *(const float4*)(hcp + j);
      pm += wm4.x * hc4.x + wm4.y * hc4.y + wm4.z * hc4.z + wm4.w * hc4.w;
      pl += wl4.x * hc4.x + wl4.y * hc4.y + wl4.z * hc4.z + wl4.w * hc4.w;
    }
  }
#pragma unroll
  for (int o = 32; o > 0; o >>= 1) {
    pm += __shfl_down(pm, o);
    pl += __shfl_down(pl, o);
  }
  if (l == 0) { rs[w] = pm; rs[4 + w] = pl; }
  __syncthreads();
  if (tid == 0) {
    float mval = rs[0] + rs[1] + rs[2] + rs[3] + bm[b];
    float lval = rs[4] + rs[5] + rs[6] + rs[7] + bl[b];
    float z = eps[b] * expf(0.5f * lval) + mval;
    out[b] = z;
    out[LAT + b] = mval;
    out[2 * LAT + b] = lval;
  }
}

extern "C" void kernel_launch(void* const* d_in, const int* in_sizes, int n_in,
                              void* d_out, int out_size, void* d_ws, size_t ws_size,
                              hipStream_t stream) {
  const int*   tok = (const int*)d_in[0];
  const float* h0  = (const float*)d_in[1];
  const float* c0  = (const float*)d_in[2];
  const float* eps = (const float*)d_in[3];
  const float* emb = (const float*)d_in[4];
  const float* Wih = (const float*)d_in[5];
  const float* Whh = (const float*)d_in[6];
  const float* bih = (const float*)d_in[7];
  const float* bhh = (const float*)d_in[8];
  const float* Wm  = (const float*)d_in[9];
  const float* bm  = (const float*)d_in[10];
  const float* Wl  = (const float*)d_in[11];
  const float* bl  = (const float*)d_in[12];
  float* out = (float*)d_out;

  char* ws = (char*)d_ws;
  unsigned long long* hbuf64 = (unsigned long long*)(ws + WS_HBUF);
  unsigned long long* hfin64 = (unsigned long long*)(ws + WS_HFIN);
  unsigned long long* cfin64 = (unsigned long long*)(ws + WS_CFIN);
  int* ctrl = (int*)(ws + WS_CTRL);

  setup_k<<<1, 1024, 0, stream>>>(tok, ctrl);

  void* args[] = {(void*)&tok, (void*)&h0, (void*)&c0, (void*)&eps, (void*)&emb,
                  (void*)&Wih, (void*)&Whh, (void*)&bih, (void*)&bhh,
                  (void*)&Wm, (void*)&bm, (void*)&Wl, (void*)&bl,
                  (void*)&hbuf64, (void*)&hfin64, (void*)&cfin64,
                  (void*)&ctrl, (void*)&out};
  hipLaunchCooperativeKernel((void*)lstm_k, dim3(NBLK), dim3(256), args, 0, stream);
}